// Round 6
// baseline (201.327 us; speedup 1.0000x reference)
//
#include <hip/hip_runtime.h>
#include <hip/hip_cooperative_groups.h>

namespace cg = cooperative_groups;

#define F 64
#define SECAP 8192
#define TCAP 2048
#define FCAP 8256
#define BLK 256

struct Params {
  const float *x, *ew, *f0w, *f0b, *f1w, *f1b, *cw, *cb;
  const int *pos, *esrc, *edst;
  float *out;
  int B, E;
  int *cnt, *mark, *TEn, *sel, *slotb, *slotn, *slot_of, *SEb, *SEd, *TEsrc2, *TEslot2;
  float *SEw, *TEw2, *AGG, *wsum, *ctab, *zf;
  int4 *zbase;
  int nzvec;
};

// ---- P0: zero {cnt,mark,TEn,AGG,wsum,ctab} + rank-sort setup (block 0) ----
__device__ __forceinline__ void phase0(const Params& p) {
  int gtid = blockIdx.x * blockDim.x + threadIdx.x;
  int nthr = gridDim.x * blockDim.x;
  for (int i = gtid; i < p.nzvec; i += nthr) p.zbase[i] = make_int4(0, 0, 0, 0);
  if (blockIdx.x == 0 && threadIdx.x < p.B) {
    int tid = threadIdx.x;
    int v = p.pos[tid], pv = p.pos[tid ^ 1];
    int rank = 0, pr = 0;
    for (int j = 0; j < p.B; ++j) { int pj = p.pos[j]; rank += (pj < v); pr += (pj < pv); }
    p.sel[rank] = v;     // unique ascending (pos values distinct)
    p.slotb[tid] = pr;   // batch = rank of partner node
    p.slotn[tid] = v;    // this output slot's target node
  }
}

// ---- P1: edge scan: SE list, TE buckets, frontier marks ----
__device__ __forceinline__ void phase1(const Params& p) {
  __shared__ int selL[64], tnL[64];
  int tid = threadIdx.x;
  int B = p.B;
  if (tid < B) { selL[tid] = p.sel[tid]; tnL[tid] = p.slotn[tid]; }
  __syncthreads();
  if (blockIdx.x == 0 && tid < B) {       // seed frontier with labeled nodes
    int n = selL[tid];
    if (atomicAdd(&p.mark[n], 1) == 0) p.slot_of[n] = atomicAdd(&p.cnt[2], 1);
  }
  int gtid = blockIdx.x * blockDim.x + tid;
  int nthr = gridDim.x * blockDim.x;
  for (int e = gtid; e < p.E; e += nthr) {
    int s = p.esrc[e], d = p.edst[e];
    float w = p.ew[e];
    int bi = -1, ti = -1;
    for (int i = 0; i < B; ++i) {
      if (s == selL[i]) bi = i;
      if (d == tnL[i]) ti = i;
    }
    if (bi >= 0) {                        // src is labeled: SE entry (for ctab)
      int idx = atomicAdd(&p.cnt[0], 1);
      if (idx < SECAP) { p.SEb[idx] = bi; p.SEd[idx] = d; p.SEw[idx] = w; }
    }
    if (ti >= 0) {                        // dst is a target: bucket + mark src
      int idx = atomicAdd(&p.TEn[ti], 1);
      if (idx < TCAP) { p.TEsrc2[ti * TCAP + idx] = s; p.TEw2[ti * TCAP + idx] = w; }
      if (atomicAdd(&p.mark[s], 1) == 0) p.slot_of[s] = atomicAdd(&p.cnt[2], 1);
    }
  }
}

// ---- P2: AGG_x scatter (edges into frontier) || ctab || TEslot ----
__device__ __forceinline__ void phase2(const Params& p) {
  int gtid = blockIdx.x * blockDim.x + threadIdx.x;
  int nthr = gridDim.x * blockDim.x;
  int E = p.E, B = p.B;
  int sen = min(p.cnt[0], SECAP);
  int total2 = E + sen + B * TCAP;
  for (int i = gtid; i < total2; i += nthr) {
    if (i < E) {
      int d = p.edst[i];
      if (p.mark[d] != 0) {
        int slot = p.slot_of[d];
        if ((unsigned)slot < (unsigned)FCAP) {
          int s = p.esrc[i];
          float w = p.ew[i];
          const float4* xs = (const float4*)(p.x + (size_t)s * F);
          float* dst = p.AGG + (size_t)slot * F;
#pragma unroll
          for (int k = 0; k < 16; ++k) {
            float4 v = xs[k];
            atomicAdd(dst + 4 * k + 0, w * v.x);
            atomicAdd(dst + 4 * k + 1, w * v.y);
            atomicAdd(dst + 4 * k + 2, w * v.z);
            atomicAdd(dst + 4 * k + 3, w * v.w);
          }
          atomicAdd(&p.wsum[slot], w);
        }
      }
    } else if (i < E + sen) {
      int j = i - E;
      int d = p.SEd[j];
      if (p.mark[d] != 0) {
        int slot = p.slot_of[d];
        if ((unsigned)slot < (unsigned)FCAP)
          atomicAdd(&p.ctab[(size_t)p.SEb[j] * FCAP + slot], p.SEw[j]);
      }
    } else {
      int j = i - E - sen;
      int t = j / TCAP, k = j - t * TCAP;
      if (t < B && k < min(p.TEn[t], TCAP)) {
        int s = p.TEsrc2[t * TCAP + k];
        int ts;
        if (s == p.sel[p.slotb[t]]) ts = -1;    // labeled-source edge -> x11 path
        else { ts = p.slot_of[s]; if ((unsigned)ts >= (unsigned)FCAP) ts = 0; }
        p.TEslot2[t * TCAP + k] = ts;
      }
    }
  }
}

// ---- P3: zf[slot] = (AGG_x@W0 + wsum*b0) @ cw0 + cb0 ----
__device__ __forceinline__ void phase3(const Params& p) {
  __shared__ float a3[4][64], t3[4][64];
  int Fn = min(p.cnt[2], FCAP);
  int tid = threadIdx.x;
  int ty = tid >> 6, h = tid & 63;
  for (int slot = blockIdx.x * 4 + ty; slot < Fn; slot += gridDim.x * 4) {
    a3[ty][h] = p.AGG[(size_t)slot * F + h];    // same-wave LDS RAW: in-order
    float acc = p.wsum[slot] * p.f0b[h];
#pragma unroll
    for (int f = 0; f < 64; ++f) acc += a3[ty][f] * p.f0w[f * 64 + h];
    t3[ty][h] = acc;
    float z = p.cb[h];
#pragma unroll
    for (int f = 0; f < 64; ++f) z += t3[ty][f] * p.cw[f * 64 + h];
    p.zf[(size_t)slot * F + h] = z;
  }
}

// ---- P4: epilogue, one 64-lane wave per output slot ----
__device__ __forceinline__ void phase4(const Params& p) {
  int t = blockIdx.x, h = threadIdx.x;
  if (t >= p.B || h >= 64) return;
  __shared__ float sh[64];
  __shared__ int esl[TCAP];
  __shared__ float ewl[TCAP];
  int b = p.slotb[t];
  int seln = p.sel[b];
  int ten = min(p.TEn[t], TCAP);
  for (int i = h; i < ten; i += 64) {
    esl[i] = p.TEslot2[t * TCAP + i];
    ewl[i] = p.TEw2[t * TCAP + i];
  }
  // d0 = x[seln]@(f1w0 - f0w0) + (f1b0 - f0b0)
  sh[h] = p.x[(size_t)seln * F + h];
  float acc = p.f1b[h] - p.f0b[h];
#pragma unroll
  for (int f = 0; f < 64; ++f) acc += sh[f] * (p.f1w[f * 64 + h] - p.f0w[f * 64 + h]);
  sh[h] = acc;                          // d0 (single-wave in-order LDS reuse)
  float g0h = 0.f;
#pragma unroll
  for (int f = 0; f < 64; ++f) g0h += sh[f] * p.cw[f * 64 + h];
  int sslot = p.slot_of[seln];
  if ((unsigned)sslot >= (unsigned)FCAP) sslot = 0;
  float cself = p.ctab[(size_t)b * FCAP + sslot];
  float h1self = fmaxf(p.zf[(size_t)sslot * F + h] + cself * g0h, 0.f);
  sh[h] = h1self;
  float x11h = p.f1b[64 + h];
#pragma unroll
  for (int f = 0; f < 64; ++f) x11h += sh[f] * p.f1w[4096 + f * 64 + h];
  // edge loop over this slot's TE bucket (~16 entries)
  float S = 0.f, wns = 0.f, wsel = 0.f;
  for (int i = 0; i < ten; ++i) {
    int slot = esl[i];
    float w = ewl[i];
    if (slot < 0) { wsel += w; continue; }
    float c = p.ctab[(size_t)b * FCAP + slot];
    float h1 = fmaxf(p.zf[(size_t)slot * F + h] + c * g0h, 0.f);
    S += w * h1;
    wns += w;
  }
  sh[h] = S;
  float a2 = wns * p.f0b[64 + h] + wsel * x11h;
#pragma unroll
  for (int f = 0; f < 64; ++f) a2 += sh[f] * p.f0w[4096 + f * 64 + h];
  sh[h] = a2;
  float o = p.cb[64 + h];
#pragma unroll
  for (int f = 0; f < 64; ++f) o += sh[f] * p.cw[4096 + f * 64 + h];
  p.out[t * F + h] = o;
}

// ---- cooperative all-in-one ----
__global__ __launch_bounds__(BLK, 2) void fused_all(Params p) {
  cg::grid_group g = cg::this_grid();
  phase0(p); g.sync();
  phase1(p); g.sync();
  phase2(p); g.sync();
  phase3(p); g.sync();
  phase4(p);
}

// ---- fallback: one dispatch per phase (stream order provides the sync) ----
__global__ __launch_bounds__(BLK) void kp0(Params p) { phase0(p); }
__global__ __launch_bounds__(BLK) void kp1(Params p) { phase1(p); }
__global__ __launch_bounds__(BLK) void kp2(Params p) { phase2(p); }
__global__ __launch_bounds__(BLK) void kp3(Params p) { phase3(p); }
__global__ __launch_bounds__(64)  void kp4(Params p) { phase4(p); }

extern "C" void kernel_launch(void* const* d_in, const int* in_sizes, int n_in,
                              void* d_out, int out_size, void* d_ws, size_t ws_size,
                              hipStream_t stream) {
  Params hp;
  hp.x = (const float*)d_in[0];
  hp.pos = (const int*)d_in[1];
  hp.esrc = (const int*)d_in[2];
  hp.edst = (const int*)d_in[3];
  hp.ew = (const float*)d_in[4];
  hp.f0w = (const float*)d_in[5];
  hp.f0b = (const float*)d_in[6];
  hp.f1w = (const float*)d_in[7];
  hp.f1b = (const float*)d_in[8];
  hp.cw = (const float*)d_in[9];
  hp.cb = (const float*)d_in[10];
  hp.out = (float*)d_out;
  const int N = in_sizes[0] / F;   // 10000
  hp.B = in_sizes[1];              // 16
  hp.E = in_sizes[2];              // 160000

  char* w = (char*)d_ws;
  size_t off = 0;
  auto take = [&](size_t nb) { size_t r = off; off += (nb + 255) & ~(size_t)255; return r; };
  // ---- zeroed region (contiguous from 0, cleared by phase0 every call) ----
  size_t o_cnt = take(256);                       // [0]=SE count, [2]=frontier count
  size_t o_mark = take((size_t)N * 4);
  size_t o_ten = take(256);
  size_t o_agg = take((size_t)FCAP * F * 4);
  size_t o_wsum = take((size_t)FCAP * 4);
  size_t o_ctab = take((size_t)hp.B * FCAP * 4);
  size_t zero_end = off;
  // ---- non-zeroed (fully overwritten before any read, guarded by counts) ----
  size_t o_sel = take(256);
  size_t o_slotb = take(256);
  size_t o_slotn = take(256);
  size_t o_slotof = take((size_t)N * 4);
  size_t o_seb = take(SECAP * 4);
  size_t o_sed = take(SECAP * 4);
  size_t o_sew = take(SECAP * 4);
  size_t o_tesrc = take((size_t)hp.B * TCAP * 4);
  size_t o_tew = take((size_t)hp.B * TCAP * 4);
  size_t o_teslot = take((size_t)hp.B * TCAP * 4);
  size_t o_zf = take((size_t)FCAP * F * 4);
  (void)ws_size;                                  // ~10 MB total; ws is far larger

  hp.cnt = (int*)(w + o_cnt);
  hp.mark = (int*)(w + o_mark);
  hp.TEn = (int*)(w + o_ten);
  hp.AGG = (float*)(w + o_agg);
  hp.wsum = (float*)(w + o_wsum);
  hp.ctab = (float*)(w + o_ctab);
  hp.sel = (int*)(w + o_sel);
  hp.slotb = (int*)(w + o_slotb);
  hp.slotn = (int*)(w + o_slotn);
  hp.slot_of = (int*)(w + o_slotof);
  hp.SEb = (int*)(w + o_seb);
  hp.SEd = (int*)(w + o_sed);
  hp.SEw = (float*)(w + o_sew);
  hp.TEsrc2 = (int*)(w + o_tesrc);
  hp.TEw2 = (float*)(w + o_tew);
  hp.TEslot2 = (int*)(w + o_teslot);
  hp.zf = (float*)(w + o_zf);
  hp.zbase = (int4*)w;
  hp.nzvec = (int)(zero_end / 16);

  // ---- cooperative path: size the grid from the runtime's own occupancy ----
  int dev = 0;
  (void)hipGetDevice(&dev);
  int numCU = 0;
  (void)hipDeviceGetAttribute(&numCU, hipDeviceAttributeMultiprocessorCount, dev);
  int maxB = 0;
  (void)hipOccupancyMaxActiveBlocksPerMultiprocessor(&maxB, (const void*)fused_all, BLK, 0);
  long long coopGrid = (long long)maxB * (long long)(numCU > 0 ? numCU : 0);
  if (coopGrid > 624) coopGrid = 624;   // no more useful parallelism than E/256
  if (coopGrid >= 64) {
    void* args[] = { &hp };
    hipError_t e = hipLaunchCooperativeKernel((const void*)fused_all,
                                              dim3((unsigned)coopGrid), dim3(BLK),
                                              args, 0, stream);
    if (e == hipSuccess) { (void)n_in; (void)out_size; return; }
    (void)hipGetLastError();            // clear sticky error, take fallback
  }

  // ---- fallback: 5 plain dispatches, identical phase bodies ----
  int nb0 = (hp.nzvec + BLK - 1) / BLK;
  if (nb0 < 1) nb0 = 1;
  if (nb0 > 2048) nb0 = 2048;
  kp0<<<nb0, BLK, 0, stream>>>(hp);
  int nb1 = (hp.E + BLK - 1) / BLK;
  if (nb1 > 2048) nb1 = 2048;
  kp1<<<nb1, BLK, 0, stream>>>(hp);
  int nb2 = (hp.E + SECAP + hp.B * TCAP + BLK - 1) / BLK;
  if (nb2 > 2048) nb2 = 2048;
  kp2<<<nb2, BLK, 0, stream>>>(hp);
  kp3<<<512, BLK, 0, stream>>>(hp);
  kp4<<<hp.B, 64, 0, stream>>>(hp);
  (void)n_in; (void)out_size;
}

// Round 7
// 93.914 us; speedup vs baseline: 2.1437x; 2.1437x over previous
//
#include <hip/hip_runtime.h>

#define F 64
#define SECAP 8192
#define TCAP 2048
#define FCAP 8256
#define BLK 256

struct Params {
  const float *x, *ew, *f0w, *f0b, *f1w, *f1b, *cw, *cb;
  const int *pos, *esrc, *edst;
  float *out;
  int B, E;
  int *cnt;            // [0]=SE count, [2]=frontier count
  int *TEn;            // per-output-slot TE counts (B)
  unsigned *bitmap;    // frontier membership, (N+31)/32 words
  int *sel, *slotb, *slot_of, *SEb, *SEd, *TEsrc2;
  float *SEw, *TEw2, *AGG, *wsum;
};

// mark node n; first marker assigns a compact slot and zeroes its AGG row+wsum
__device__ __forceinline__ void mark_assign(const Params& p, int n) {
  unsigned bit = 1u << (n & 31);
  unsigned old = atomicOr(&p.bitmap[n >> 5], bit);
  if (!(old & bit)) {
    int sl = atomicAdd(&p.cnt[2], 1);
    if (sl < FCAP) {
      p.slot_of[n] = sl;
      float4* row = (float4*)(p.AGG + (size_t)sl * F);
#pragma unroll
      for (int k = 0; k < 16; ++k) row[k] = make_float4(0.f, 0.f, 0.f, 0.f);
      p.wsum[sl] = 0.f;
    } else {
      p.slot_of[n] = 0;   // pathological overflow guard
    }
  }
}

// ---- K1: edge scan. Each block self-computes the pos rank table (no setup
// ---- kernel). Produces SE list, per-slot TE buckets, frontier bitmap+slots.
__global__ __launch_bounds__(BLK) void kp_scan(Params p) {
  __shared__ int posL[16], rankL[16];
  const int tid = threadIdx.x;
  const int B = p.B;
  if (tid < B) {
    int v = p.pos[tid];
    int rank = 0;
    for (int j = 0; j < B; ++j) rank += (p.pos[j] < v);
    posL[tid] = v;
    rankL[tid] = rank;
  }
  __syncthreads();
  if (blockIdx.x == 0 && tid < B) {
    p.sel[rankL[tid]] = posL[tid];      // unique ascending (values distinct)
    p.slotb[tid] = rankL[tid ^ 1];      // batch = rank of partner node
    mark_assign(p, posL[tid]);          // seed frontier with labeled nodes
  }
  int gtid = blockIdx.x * BLK + tid;
  int nthr = gridDim.x * BLK;
  for (int e = gtid; e < p.E; e += nthr) {
    int s = p.esrc[e], d = p.edst[e];
    float w = p.ew[e];
    int bi = -1, ti = -1;
#pragma unroll
    for (int j = 0; j < 16; ++j) {
      if (j < B) {
        if (s == posL[j]) bi = rankL[j];
        if (d == posL[j]) ti = j;
      }
    }
    if (bi >= 0) {                      // src is labeled: SE entry
      int idx = atomicAdd(&p.cnt[0], 1);
      if (idx < SECAP) { p.SEb[idx] = bi; p.SEd[idx] = d; p.SEw[idx] = w; }
    }
    if (ti >= 0) {                      // dst is a target: bucket + mark src
      int idx = atomicAdd(&p.TEn[ti], 1);
      if (idx < TCAP) { p.TEsrc2[ti * TCAP + idx] = s; p.TEw2[ti * TCAP + idx] = w; }
      mark_assign(p, s);
    }
  }
}

// ---- K2: AGG_x[slot(d)] += w * x[src] over edges into frontier nodes ----
__global__ __launch_bounds__(BLK) void kp_agg(Params p) {
  int gtid = blockIdx.x * BLK + threadIdx.x;
  int nthr = gridDim.x * BLK;
  for (int e = gtid; e < p.E; e += nthr) {
    int d = p.edst[e];
    if (!((p.bitmap[d >> 5] >> (d & 31)) & 1u)) continue;
    int sl = p.slot_of[d];
    if ((unsigned)sl >= (unsigned)FCAP) continue;
    int s = p.esrc[e];
    float w = p.ew[e];
    const float4* xs = (const float4*)(p.x + (size_t)s * F);
    float* dst = p.AGG + (size_t)sl * F;
#pragma unroll
    for (int k = 0; k < 16; ++k) {
      float4 v = xs[k];
      atomicAdd(dst + 4 * k + 0, w * v.x);
      atomicAdd(dst + 4 * k + 1, w * v.y);
      atomicAdd(dst + 4 * k + 2, w * v.z);
      atomicAdd(dst + 4 * k + 3, w * v.w);
    }
    atomicAdd(&p.wsum[sl], w);
  }
}

#define MV4(res, init, vec, mat)                        \
  {                                                     \
    float s0_ = 0.f, s1_ = 0.f, s2_ = 0.f, s3_ = 0.f;   \
    _Pragma("unroll")                                   \
    for (int f_ = 0; f_ < 64; f_ += 4) {                \
      s0_ += (vec)[f_ + 0] * (mat)[(f_ + 0) * 64 + h];  \
      s1_ += (vec)[f_ + 1] * (mat)[(f_ + 1) * 64 + h];  \
      s2_ += (vec)[f_ + 2] * (mat)[(f_ + 2) * 64 + h];  \
      s3_ += (vec)[f_ + 3] * (mat)[(f_ + 3) * 64 + h];  \
    }                                                   \
    res = (init) + ((s0_ + s1_) + (s2_ + s3_));         \
  }

// ---- K3: epilogue. One 64-lane wave per output slot: private c-row in LDS,
// ---- on-the-fly zf transform of ~17 slots, final matvecs -> out row.
__global__ __launch_bounds__(64) void kp_epi(Params p) {
  __shared__ float cL[FCAP];            // c_{b,slot} for this block's batch b
  __shared__ float sh[64], a1[64], a2[64];
  __shared__ int slL[TCAP];
  __shared__ float twL[TCAP];
  const int t = blockIdx.x, h = threadIdx.x;
  const int b = p.slotb[t];
  const int seln = p.sel[b];            // labeled node of batch b
  const int Fn = min(p.cnt[2], FCAP);
  for (int i = h; i < Fn; i += 64) cL[i] = 0.f;
  // build c-row: SE entries of batch b landing on frontier nodes (LDS atomics)
  int sen = min(p.cnt[0], SECAP);
  for (int i = h; i < sen; i += 64) {
    if (p.SEb[i] == b) {
      int d = p.SEd[i];
      if ((p.bitmap[d >> 5] >> (d & 31)) & 1u) {
        int sl = p.slot_of[d];
        if ((unsigned)sl < (unsigned)FCAP) atomicAdd(&cL[sl], p.SEw[i]);
      }
    }
  }
  // stage TE bucket: slot (or -1 for labeled-src) + weight
  int ten = min(p.TEn[t], TCAP);
  for (int i = h; i < ten; i += 64) {
    int s = p.TEsrc2[t * TCAP + i];
    int sl;
    if (s == seln) sl = -1;
    else { sl = p.slot_of[s]; if ((unsigned)sl >= (unsigned)FCAP) sl = 0; }
    slL[i] = sl;
    twL[i] = p.TEw2[t * TCAP + i];
  }
  __syncthreads();                      // single wave: cheap s_barrier
  // d0 = x[seln]@(f1w0-f0w0) + (f1b0-f0b0); g0 = d0@cw0
  sh[h] = p.x[(size_t)seln * F + h];
  float d0h;
  {
    float s0_ = 0.f, s1_ = 0.f, s2_ = 0.f, s3_ = 0.f;
#pragma unroll
    for (int f_ = 0; f_ < 64; f_ += 4) {
      s0_ += sh[f_ + 0] * (p.f1w[(f_ + 0) * 64 + h] - p.f0w[(f_ + 0) * 64 + h]);
      s1_ += sh[f_ + 1] * (p.f1w[(f_ + 1) * 64 + h] - p.f0w[(f_ + 1) * 64 + h]);
      s2_ += sh[f_ + 2] * (p.f1w[(f_ + 2) * 64 + h] - p.f0w[(f_ + 2) * 64 + h]);
      s3_ += sh[f_ + 3] * (p.f1w[(f_ + 3) * 64 + h] - p.f0w[(f_ + 3) * 64 + h]);
    }
    d0h = (p.f1b[h] - p.f0b[h]) + ((s0_ + s1_) + (s2_ + s3_));
  }
  sh[h] = d0h;
  float g0h;
  MV4(g0h, 0.f, sh, p.cw);
  // h1 at slot sl: z = (AGG@W0 + wsum*b0)@cw0 + cb0; h1 = relu(z + c*g0)
  auto h1_at = [&](int sl) -> float {
    a1[h] = p.AGG[(size_t)sl * F + h];
    float wsv = p.wsum[sl];
    float t1;
    MV4(t1, wsv * p.f0b[h], a1, p.f0w);
    a2[h] = t1;
    float z;
    MV4(z, p.cb[h], a2, p.cw);
    return fmaxf(z + cL[sl] * g0h, 0.f);
  };
  // x11 = h1[b, seln] @ f1w1 + f1b1
  int sslot = p.slot_of[seln];
  if ((unsigned)sslot >= (unsigned)FCAP) sslot = 0;
  float h1self = h1_at(sslot);
  sh[h] = h1self;
  float x11h;
  MV4(x11h, p.f1b[64 + h], sh, (p.f1w + 4096));
  // TE edge loop
  float S = 0.f, wns = 0.f, wsel = 0.f;
  for (int i = 0; i < ten; ++i) {
    int sl = slL[i];
    float w = twL[i];
    if (sl < 0) { wsel += w; continue; }
    float h1 = h1_at(sl);
    S += w * h1;
    wns += w;
  }
  sh[h] = S;
  float a2h;
  MV4(a2h, wns * p.f0b[64 + h] + wsel * x11h, sh, (p.f0w + 4096));
  sh[h] = a2h;
  float o;
  MV4(o, p.cb[64 + h], sh, (p.cw + 4096));
  p.out[t * F + h] = o;
}

extern "C" void kernel_launch(void* const* d_in, const int* in_sizes, int n_in,
                              void* d_out, int out_size, void* d_ws, size_t ws_size,
                              hipStream_t stream) {
  Params hp;
  hp.x = (const float*)d_in[0];
  hp.pos = (const int*)d_in[1];
  hp.esrc = (const int*)d_in[2];
  hp.edst = (const int*)d_in[3];
  hp.ew = (const float*)d_in[4];
  hp.f0w = (const float*)d_in[5];
  hp.f0b = (const float*)d_in[6];
  hp.f1w = (const float*)d_in[7];
  hp.f1b = (const float*)d_in[8];
  hp.cw = (const float*)d_in[9];
  hp.cb = (const float*)d_in[10];
  hp.out = (float*)d_out;
  const int N = in_sizes[0] / F;   // 10000
  hp.B = in_sizes[1];              // 16
  hp.E = in_sizes[2];              // 160000

  char* w = (char*)d_ws;
  size_t off = 0;
  auto take = [&](size_t nb) { size_t r = off; off += (nb + 255) & ~(size_t)255; return r; };
  // ---- zeroed by ONE small memset (contiguous from 0): cnt, TEn, bitmap ----
  size_t o_cnt = take(256);
  size_t o_ten = take(256);
  size_t o_bitmap = take(((size_t)N + 31) / 32 * 4);
  size_t zero_end = off;
  // ---- not zeroed (lazily initialized / fully overwritten before read) ----
  size_t o_sel = take(256);
  size_t o_slotb = take(256);
  size_t o_slotof = take((size_t)N * 4);
  size_t o_seb = take(SECAP * 4);
  size_t o_sed = take(SECAP * 4);
  size_t o_sew = take(SECAP * 4);
  size_t o_tesrc = take((size_t)hp.B * TCAP * 4);
  size_t o_tew = take((size_t)hp.B * TCAP * 4);
  size_t o_agg = take((size_t)FCAP * F * 4);
  size_t o_wsum = take((size_t)FCAP * 4);
  (void)ws_size;                   // ~3.5 MB total; ws is far larger

  hp.cnt = (int*)(w + o_cnt);
  hp.TEn = (int*)(w + o_ten);
  hp.bitmap = (unsigned*)(w + o_bitmap);
  hp.sel = (int*)(w + o_sel);
  hp.slotb = (int*)(w + o_slotb);
  hp.slot_of = (int*)(w + o_slotof);
  hp.SEb = (int*)(w + o_seb);
  hp.SEd = (int*)(w + o_sed);
  hp.SEw = (float*)(w + o_sew);
  hp.TEsrc2 = (int*)(w + o_tesrc);
  hp.TEw2 = (float*)(w + o_tew);
  hp.AGG = (float*)(w + o_agg);
  hp.wsum = (float*)(w + o_wsum);

  // node 1: tiny memset (~2 KB)
  hipMemsetAsync(d_ws, 0, zero_end, stream);
  // node 2: edge scan
  int nbE = (hp.E + BLK - 1) / BLK;
  if (nbE > 2048) nbE = 2048;
  kp_scan<<<nbE, BLK, 0, stream>>>(hp);
  // node 3: frontier aggregation
  kp_agg<<<nbE, BLK, 0, stream>>>(hp);
  // node 4: epilogue
  kp_epi<<<hp.B, 64, 0, stream>>>(hp);
  (void)n_in; (void)out_size;
}

// Round 8
// 69.294 us; speedup vs baseline: 2.9054x; 1.3553x over previous
//
#include <hip/hip_runtime.h>

#define F 64
#define SECAP 8192
#define TCAP 2048
#define FCAP 8256
#define BLK 256
#define EPIW 4   // waves per kp_epi block

struct Params {
  const float *x, *ew, *f0w, *f0b, *f1w, *f1b, *cw, *cb;
  const int *pos, *esrc, *edst;
  float *out;
  int B, E;
  int *cnt;            // [0]=SE count, [2]=frontier count
  int *TEn;            // per-output-slot TE counts (B)
  unsigned *bitmap;    // frontier membership, (N+31)/32 words
  int *sel, *slotb, *slot_of, *SEb, *SEd, *TEsrc2;
  float *SEw, *TEw2, *AGG, *wsum;
};

// mark node n; first marker assigns a compact slot and zeroes its AGG row+wsum
__device__ __forceinline__ void mark_assign(const Params& p, int n) {
  unsigned bit = 1u << (n & 31);
  unsigned old = atomicOr(&p.bitmap[n >> 5], bit);
  if (!(old & bit)) {
    int sl = atomicAdd(&p.cnt[2], 1);
    if (sl < FCAP) {
      p.slot_of[n] = sl;
      float4* row = (float4*)(p.AGG + (size_t)sl * F);
#pragma unroll
      for (int k = 0; k < 16; ++k) row[k] = make_float4(0.f, 0.f, 0.f, 0.f);
      p.wsum[sl] = 0.f;
    } else {
      p.slot_of[n] = 0;   // pathological overflow guard
    }
  }
}

// ---- K1: edge scan. Each block self-computes the pos rank table. Produces
// ---- SE list, per-slot TE buckets, frontier bitmap + compact slots.
__global__ __launch_bounds__(BLK) void kp_scan(Params p) {
  __shared__ int posL[16], rankL[16];
  const int tid = threadIdx.x;
  const int B = p.B;
  if (tid < B) {
    int v = p.pos[tid];
    int rank = 0;
    for (int j = 0; j < B; ++j) rank += (p.pos[j] < v);
    posL[tid] = v;
    rankL[tid] = rank;
  }
  __syncthreads();
  if (blockIdx.x == 0 && tid < B) {
    p.sel[rankL[tid]] = posL[tid];      // unique ascending (values distinct)
    p.slotb[tid] = rankL[tid ^ 1];      // batch = rank of partner node
    mark_assign(p, posL[tid]);          // seed frontier with labeled nodes
  }
  int gtid = blockIdx.x * BLK + tid;
  int nthr = gridDim.x * BLK;
  for (int e = gtid; e < p.E; e += nthr) {
    int s = p.esrc[e], d = p.edst[e];
    float w = p.ew[e];
    int bi = -1, ti = -1;
#pragma unroll
    for (int j = 0; j < 16; ++j) {
      if (j < B) {
        if (s == posL[j]) bi = rankL[j];
        if (d == posL[j]) ti = j;
      }
    }
    if (bi >= 0) {                      // src is labeled: SE entry
      int idx = atomicAdd(&p.cnt[0], 1);
      if (idx < SECAP) { p.SEb[idx] = bi; p.SEd[idx] = d; p.SEw[idx] = w; }
    }
    if (ti >= 0) {                      // dst is a target: bucket + mark src
      int idx = atomicAdd(&p.TEn[ti], 1);
      if (idx < TCAP) { p.TEsrc2[ti * TCAP + idx] = s; p.TEw2[ti * TCAP + idx] = w; }
      mark_assign(p, s);
    }
  }
}

// ---- K2: AGG_x[slot(d)] += w * x[src] over edges into frontier nodes ----
__global__ __launch_bounds__(BLK) void kp_agg(Params p) {
  int gtid = blockIdx.x * BLK + threadIdx.x;
  int nthr = gridDim.x * BLK;
  for (int e = gtid; e < p.E; e += nthr) {
    int d = p.edst[e];
    if (!((p.bitmap[d >> 5] >> (d & 31)) & 1u)) continue;
    int sl = p.slot_of[d];
    if ((unsigned)sl >= (unsigned)FCAP) continue;
    int s = p.esrc[e];
    float w = p.ew[e];
    const float4* xs = (const float4*)(p.x + (size_t)s * F);
    float* dst = p.AGG + (size_t)sl * F;
#pragma unroll
    for (int k = 0; k < 16; ++k) {
      float4 v = xs[k];
      atomicAdd(dst + 4 * k + 0, w * v.x);
      atomicAdd(dst + 4 * k + 1, w * v.y);
      atomicAdd(dst + 4 * k + 2, w * v.z);
      atomicAdd(dst + 4 * k + 3, w * v.w);
    }
    atomicAdd(&p.wsum[sl], w);
  }
}

// broadcast matvec: res = init + sum_f vec[f]*mat[f*64+h].
// vec is an LDS float[64] read as float4 broadcasts (16 ds_read_b128).
#define MVB(res, init, vecp, mat)                         \
  {                                                       \
    float a0_ = 0.f, a1_ = 0.f, a2_ = 0.f, a3_ = 0.f;     \
    _Pragma("unroll")                                     \
    for (int q_ = 0; q_ < 16; ++q_) {                     \
      float4 vv_ = ((const float4*)(vecp))[q_];           \
      a0_ += vv_.x * (mat)[(4 * q_ + 0) * 64 + h];        \
      a1_ += vv_.y * (mat)[(4 * q_ + 1) * 64 + h];        \
      a2_ += vv_.z * (mat)[(4 * q_ + 2) * 64 + h];        \
      a3_ += vv_.w * (mat)[(4 * q_ + 3) * 64 + h];        \
    }                                                     \
    res = (init) + ((a0_ + a1_) + (a2_ + a3_));           \
  }

// ---- K3: epilogue. One block (4 waves) per output slot. Waves split the TE
// ---- edge loop; d0/g0/h1self/x11 computed per-wave redundantly (parallel).
__global__ __launch_bounds__(BLK) void kp_epi(Params p) {
  __shared__ float cL[FCAP];            // c_{b,slot} for this block's batch b
  __shared__ __align__(16) float v0[EPIW][64], v1[EPIW][64];
  __shared__ __align__(16) float Sp[EPIW][64];
  __shared__ float wnsL[EPIW], wselL[EPIW];
  __shared__ int slL[TCAP];
  __shared__ float twL[TCAP];
  const int t = blockIdx.x;
  const int tid = threadIdx.x;
  const int h = tid & 63, wv = tid >> 6;
  const int b = p.slotb[t];
  const int seln = p.sel[b];            // labeled node of batch b
  const int Fn = min(p.cnt[2], FCAP);
  for (int i = tid; i < Fn; i += BLK) cL[i] = 0.f;
  __syncthreads();
  // build c-row: SE entries of batch b landing on frontier nodes (LDS atomics)
  int sen = min(p.cnt[0], SECAP);
  for (int i = tid; i < sen; i += BLK) {
    if (p.SEb[i] == b) {
      int d = p.SEd[i];
      if ((p.bitmap[d >> 5] >> (d & 31)) & 1u) {
        int sl = p.slot_of[d];
        if ((unsigned)sl < (unsigned)FCAP) atomicAdd(&cL[sl], p.SEw[i]);
      }
    }
  }
  // stage TE bucket: slot (or -1 for labeled-src) + weight
  int ten = min(p.TEn[t], TCAP);
  for (int i = tid; i < ten; i += BLK) {
    int s = p.TEsrc2[t * TCAP + i];
    int sl;
    if (s == seln) sl = -1;
    else { sl = p.slot_of[s]; if ((unsigned)sl >= (unsigned)FCAP) sl = 0; }
    slL[i] = sl;
    twL[i] = p.TEw2[t * TCAP + i];
  }
  __syncthreads();
  // ---- per-wave (redundant, parallel): d0, g0, h1self, x11 ----
  v0[wv][h] = p.x[(size_t)seln * F + h];   // single-wave in-order LDS reuse
  float d0h;
  {
    float a0_ = 0.f, a1_ = 0.f, a2_ = 0.f, a3_ = 0.f;
#pragma unroll
    for (int q = 0; q < 16; ++q) {
      float4 vv = ((const float4*)(v0[wv]))[q];
      a0_ += vv.x * (p.f1w[(4 * q + 0) * 64 + h] - p.f0w[(4 * q + 0) * 64 + h]);
      a1_ += vv.y * (p.f1w[(4 * q + 1) * 64 + h] - p.f0w[(4 * q + 1) * 64 + h]);
      a2_ += vv.z * (p.f1w[(4 * q + 2) * 64 + h] - p.f0w[(4 * q + 2) * 64 + h]);
      a3_ += vv.w * (p.f1w[(4 * q + 3) * 64 + h] - p.f0w[(4 * q + 3) * 64 + h]);
    }
    d0h = (p.f1b[h] - p.f0b[h]) + ((a0_ + a1_) + (a2_ + a3_));
  }
  v0[wv][h] = d0h;
  float g0h;
  MVB(g0h, 0.f, v0[wv], p.cw);
  // h1 at slot sl: z = (AGG@W0 + wsum*b0)@cw0 + cb0; h1 = relu(z + c*g0)
  auto h1_at = [&](int sl) -> float {
    v0[wv][h] = p.AGG[(size_t)sl * F + h];
    float t1;
    MVB(t1, p.wsum[sl] * p.f0b[h], v0[wv], p.f0w);
    v1[wv][h] = t1;
    float z;
    MVB(z, p.cb[h], v1[wv], p.cw);
    return fmaxf(z + cL[sl] * g0h, 0.f);
  };
  int sslot = p.slot_of[seln];
  if ((unsigned)sslot >= (unsigned)FCAP) sslot = 0;
  float h1self = h1_at(sslot);
  v0[wv][h] = h1self;
  float x11h;
  MVB(x11h, p.f1b[64 + h], v0[wv], (p.f1w + 4096));
  // ---- wave-split TE edge loop ----
  float S = 0.f, wns = 0.f, wsel = 0.f;
  for (int i = wv; i < ten; i += EPIW) {
    int sl = slL[i];
    float w = twL[i];
    if (sl < 0) { wsel += w; continue; }
    float h1 = h1_at(sl);
    S += w * h1;
    wns += w;
  }
  Sp[wv][h] = S;
  if (h == 0) { wnsL[wv] = wns; wselL[wv] = wsel; }
  __syncthreads();
  // ---- wave 0: combine partials, final two matvecs, store ----
  if (wv == 0) {
    float Sh = Sp[0][h] + Sp[1][h] + Sp[2][h] + Sp[3][h];
    float wnsT = wnsL[0] + wnsL[1] + wnsL[2] + wnsL[3];
    float wselT = wselL[0] + wselL[1] + wselL[2] + wselL[3];
    v0[0][h] = Sh;
    float a2h;
    MVB(a2h, wnsT * p.f0b[64 + h] + wselT * x11h, v0[0], (p.f0w + 4096));
    v1[0][h] = a2h;
    float o;
    MVB(o, p.cb[64 + h], v1[0], (p.cw + 4096));
    p.out[t * F + h] = o;
  }
}

extern "C" void kernel_launch(void* const* d_in, const int* in_sizes, int n_in,
                              void* d_out, int out_size, void* d_ws, size_t ws_size,
                              hipStream_t stream) {
  Params hp;
  hp.x = (const float*)d_in[0];
  hp.pos = (const int*)d_in[1];
  hp.esrc = (const int*)d_in[2];
  hp.edst = (const int*)d_in[3];
  hp.ew = (const float*)d_in[4];
  hp.f0w = (const float*)d_in[5];
  hp.f0b = (const float*)d_in[6];
  hp.f1w = (const float*)d_in[7];
  hp.f1b = (const float*)d_in[8];
  hp.cw = (const float*)d_in[9];
  hp.cb = (const float*)d_in[10];
  hp.out = (float*)d_out;
  const int N = in_sizes[0] / F;   // 10000
  hp.B = in_sizes[1];              // 16
  hp.E = in_sizes[2];              // 160000

  char* w = (char*)d_ws;
  size_t off = 0;
  auto take = [&](size_t nb) { size_t r = off; off += (nb + 255) & ~(size_t)255; return r; };
  // ---- zeroed by ONE small memset (contiguous from 0): cnt, TEn, bitmap ----
  size_t o_cnt = take(256);
  size_t o_ten = take(256);
  size_t o_bitmap = take(((size_t)N + 31) / 32 * 4);
  size_t zero_end = off;
  // ---- not zeroed (lazily initialized / fully overwritten before read) ----
  size_t o_sel = take(256);
  size_t o_slotb = take(256);
  size_t o_slotof = take((size_t)N * 4);
  size_t o_seb = take(SECAP * 4);
  size_t o_sed = take(SECAP * 4);
  size_t o_sew = take(SECAP * 4);
  size_t o_tesrc = take((size_t)hp.B * TCAP * 4);
  size_t o_tew = take((size_t)hp.B * TCAP * 4);
  size_t o_agg = take((size_t)FCAP * F * 4);
  size_t o_wsum = take((size_t)FCAP * 4);
  (void)ws_size;                   // ~3.5 MB total; ws is far larger

  hp.cnt = (int*)(w + o_cnt);
  hp.TEn = (int*)(w + o_ten);
  hp.bitmap = (unsigned*)(w + o_bitmap);
  hp.sel = (int*)(w + o_sel);
  hp.slotb = (int*)(w + o_slotb);
  hp.slot_of = (int*)(w + o_slotof);
  hp.SEb = (int*)(w + o_seb);
  hp.SEd = (int*)(w + o_sed);
  hp.SEw = (float*)(w + o_sew);
  hp.TEsrc2 = (int*)(w + o_tesrc);
  hp.TEw2 = (float*)(w + o_tew);
  hp.AGG = (float*)(w + o_agg);
  hp.wsum = (float*)(w + o_wsum);

  // node 1: tiny memset (~2 KB)
  hipMemsetAsync(d_ws, 0, zero_end, stream);
  // node 2: edge scan
  int nbE = (hp.E + BLK - 1) / BLK;
  if (nbE > 2048) nbE = 2048;
  kp_scan<<<nbE, BLK, 0, stream>>>(hp);
  // node 3: frontier aggregation
  kp_agg<<<nbE, BLK, 0, stream>>>(hp);
  // node 4: epilogue (16 blocks x 4 waves)
  kp_epi<<<hp.B, BLK, 0, stream>>>(hp);
  (void)n_in; (void)out_size;
}

// Round 9
// 55.991 us; speedup vs baseline: 3.5957x; 1.2376x over previous
//
#include <hip/hip_runtime.h>

#define F 64
#define SECAP 8192
#define TCAP 2048
#define FCAP 8256
#define BLK 256
#define EPIW 4   // waves per kp_epi block

struct Params {
  const float *x, *ew, *f0w, *f0b, *f1w, *f1b, *cw, *cb;
  const int *pos, *esrc, *edst;
  float *out;
  int B, E;
  int *cnt;            // [0]=SE count, [2]=frontier count
  int *TEn;            // per-output-slot TE counts (B)
  unsigned *bitmap;    // frontier membership, (N+31)/32 words
  int *sel, *slotb, *slot_of, *SEb, *SEd, *TEsrc2;
  float *SEw, *TEw2, *AGG, *wsum, *zf;
};

// mark node n; first marker assigns a compact slot and zeroes its AGG row+wsum
__device__ __forceinline__ void mark_assign(const Params& p, int n) {
  unsigned bit = 1u << (n & 31);
  unsigned old = atomicOr(&p.bitmap[n >> 5], bit);
  if (!(old & bit)) {
    int sl = atomicAdd(&p.cnt[2], 1);
    if (sl < FCAP) {
      p.slot_of[n] = sl;
      float4* row = (float4*)(p.AGG + (size_t)sl * F);
#pragma unroll
      for (int k = 0; k < 16; ++k) row[k] = make_float4(0.f, 0.f, 0.f, 0.f);
      p.wsum[sl] = 0.f;
    } else {
      p.slot_of[n] = 0;   // pathological overflow guard
    }
  }
}

// ---- K1: edge scan. Each block self-computes the pos rank table. Produces
// ---- SE list, per-slot TE buckets, frontier bitmap + compact slots.
__global__ __launch_bounds__(BLK) void kp_scan(Params p) {
  __shared__ int posL[16], rankL[16];
  const int tid = threadIdx.x;
  const int B = p.B;
  if (tid < B) {
    int v = p.pos[tid];
    int rank = 0;
    for (int j = 0; j < B; ++j) rank += (p.pos[j] < v);
    posL[tid] = v;
    rankL[tid] = rank;
  }
  __syncthreads();
  if (blockIdx.x == 0 && tid < B) {
    p.sel[rankL[tid]] = posL[tid];      // unique ascending (values distinct)
    p.slotb[tid] = rankL[tid ^ 1];      // batch = rank of partner node
    mark_assign(p, posL[tid]);          // seed frontier with labeled nodes
  }
  int gtid = blockIdx.x * BLK + tid;
  int nthr = gridDim.x * BLK;
  for (int e = gtid; e < p.E; e += nthr) {
    int s = p.esrc[e], d = p.edst[e];
    float w = p.ew[e];
    int bi = -1, ti = -1;
#pragma unroll
    for (int j = 0; j < 16; ++j) {
      if (j < B) {
        if (s == posL[j]) bi = rankL[j];
        if (d == posL[j]) ti = j;
      }
    }
    if (bi >= 0) {                      // src is labeled: SE entry
      int idx = atomicAdd(&p.cnt[0], 1);
      if (idx < SECAP) { p.SEb[idx] = bi; p.SEd[idx] = d; p.SEw[idx] = w; }
    }
    if (ti >= 0) {                      // dst is a target: bucket + mark src
      int idx = atomicAdd(&p.TEn[ti], 1);
      if (idx < TCAP) { p.TEsrc2[ti * TCAP + idx] = s; p.TEw2[ti * TCAP + idx] = w; }
      mark_assign(p, s);
    }
  }
}

// ---- K2: AGG_x[slot(d)] += w * x[src] over edges into frontier nodes ----
__global__ __launch_bounds__(BLK) void kp_agg(Params p) {
  int gtid = blockIdx.x * BLK + threadIdx.x;
  int nthr = gridDim.x * BLK;
  for (int e = gtid; e < p.E; e += nthr) {
    int d = p.edst[e];
    if (!((p.bitmap[d >> 5] >> (d & 31)) & 1u)) continue;
    int sl = p.slot_of[d];
    if ((unsigned)sl >= (unsigned)FCAP) continue;
    int s = p.esrc[e];
    float w = p.ew[e];
    const float4* xs = (const float4*)(p.x + (size_t)s * F);
    float* dst = p.AGG + (size_t)sl * F;
#pragma unroll
    for (int k = 0; k < 16; ++k) {
      float4 v = xs[k];
      atomicAdd(dst + 4 * k + 0, w * v.x);
      atomicAdd(dst + 4 * k + 1, w * v.y);
      atomicAdd(dst + 4 * k + 2, w * v.z);
      atomicAdd(dst + 4 * k + 3, w * v.w);
    }
    atomicAdd(&p.wsum[sl], w);
  }
}

// broadcast matvec: res = init + sum_f vec[f]*mat[f*64+h].
// vec is an LDS float[64] read as float4 broadcasts (16 ds_read_b128).
#define MVB(res, init, vecp, mat)                         \
  {                                                       \
    float a0_ = 0.f, a1_ = 0.f, a2_ = 0.f, a3_ = 0.f;     \
    _Pragma("unroll")                                     \
    for (int q_ = 0; q_ < 16; ++q_) {                     \
      float4 vv_ = ((const float4*)(vecp))[q_];           \
      a0_ += vv_.x * (mat)[(4 * q_ + 0) * 64 + h];        \
      a1_ += vv_.y * (mat)[(4 * q_ + 1) * 64 + h];        \
      a2_ += vv_.z * (mat)[(4 * q_ + 2) * 64 + h];        \
      a3_ += vv_.w * (mat)[(4 * q_ + 3) * 64 + h];        \
    }                                                     \
    res = (init) + ((a0_ + a1_) + (a2_ + a3_));           \
  }

// ---- K3: zf[slot] = (AGG_x@W0 + wsum*b0) @ cw0 + cb0, parallel over slots ----
__global__ __launch_bounds__(BLK) void kp_zf(Params p) {
  __shared__ __align__(16) float a[4][64], tt[4][64];
  const int Fn = min(p.cnt[2], FCAP);
  const int ty = threadIdx.x >> 6, h = threadIdx.x & 63;
  for (int sl = blockIdx.x * 4 + ty; sl < Fn; sl += gridDim.x * 4) {
    a[ty][h] = p.AGG[(size_t)sl * F + h];   // same-wave in-order LDS RAW
    float t1;
    MVB(t1, p.wsum[sl] * p.f0b[h], a[ty], p.f0w);
    tt[ty][h] = t1;
    float z;
    MVB(z, p.cb[h], tt[ty], p.cw);
    p.zf[(size_t)sl * F + h] = z;
  }
}

// ---- K4: epilogue. One block (4 waves) per output slot. TE loop is now
// ---- zf-row loads + FMA (no matvecs in the loop).
__global__ __launch_bounds__(BLK) void kp_epi(Params p) {
  __shared__ float cL[FCAP];            // c_{b,slot} for this block's batch b
  __shared__ __align__(16) float v0[EPIW][64], v1[EPIW][64];
  __shared__ __align__(16) float Sp[EPIW][64];
  __shared__ float wnsL[EPIW], wselL[EPIW];
  __shared__ int slL[TCAP];
  __shared__ float twL[TCAP];
  const int t = blockIdx.x;
  const int tid = threadIdx.x;
  const int h = tid & 63, wv = tid >> 6;
  const int b = p.slotb[t];
  const int seln = p.sel[b];            // labeled node of batch b
  const int Fn = min(p.cnt[2], FCAP);
  for (int i = tid; i < Fn; i += BLK) cL[i] = 0.f;
  __syncthreads();
  // build c-row: SE entries of batch b landing on frontier nodes (LDS atomics)
  int sen = min(p.cnt[0], SECAP);
  for (int i = tid; i < sen; i += BLK) {
    if (p.SEb[i] == b) {
      int d = p.SEd[i];
      if ((p.bitmap[d >> 5] >> (d & 31)) & 1u) {
        int sl = p.slot_of[d];
        if ((unsigned)sl < (unsigned)FCAP) atomicAdd(&cL[sl], p.SEw[i]);
      }
    }
  }
  // stage TE bucket: slot (or -1 for labeled-src) + weight
  int ten = min(p.TEn[t], TCAP);
  for (int i = tid; i < ten; i += BLK) {
    int s = p.TEsrc2[t * TCAP + i];
    int sl;
    if (s == seln) sl = -1;
    else { sl = p.slot_of[s]; if ((unsigned)sl >= (unsigned)FCAP) sl = 0; }
    slL[i] = sl;
    twL[i] = p.TEw2[t * TCAP + i];
  }
  __syncthreads();
  // ---- per-wave (redundant, parallel): d0, g0, h1self, x11 ----
  v0[wv][h] = p.x[(size_t)seln * F + h];
  float d0h;
  {
    float a0_ = 0.f, a1_ = 0.f, a2_ = 0.f, a3_ = 0.f;
#pragma unroll
    for (int q = 0; q < 16; ++q) {
      float4 vv = ((const float4*)(v0[wv]))[q];
      a0_ += vv.x * (p.f1w[(4 * q + 0) * 64 + h] - p.f0w[(4 * q + 0) * 64 + h]);
      a1_ += vv.y * (p.f1w[(4 * q + 1) * 64 + h] - p.f0w[(4 * q + 1) * 64 + h]);
      a2_ += vv.z * (p.f1w[(4 * q + 2) * 64 + h] - p.f0w[(4 * q + 2) * 64 + h]);
      a3_ += vv.w * (p.f1w[(4 * q + 3) * 64 + h] - p.f0w[(4 * q + 3) * 64 + h]);
    }
    d0h = (p.f1b[h] - p.f0b[h]) + ((a0_ + a1_) + (a2_ + a3_));
  }
  v0[wv][h] = d0h;
  float g0h;
  MVB(g0h, 0.f, v0[wv], p.cw);
  // h1self = relu(zf[sslot] + c_self*g0); x11 = h1self @ f1w1 + f1b1
  int sslot = p.slot_of[seln];
  if ((unsigned)sslot >= (unsigned)FCAP) sslot = 0;
  float h1self = fmaxf(p.zf[(size_t)sslot * F + h] + cL[sslot] * g0h, 0.f);
  v0[wv][h] = h1self;
  float x11h;
  MVB(x11h, p.f1b[64 + h], v0[wv], (p.f1w + 4096));
  // ---- wave-split TE edge loop: one zf row load + FMA per entry ----
  float S = 0.f, wns = 0.f, wsel = 0.f;
  for (int i = wv; i < ten; i += EPIW) {
    int sl = slL[i];
    float w = twL[i];
    if (sl < 0) { wsel += w; continue; }
    float h1 = fmaxf(p.zf[(size_t)sl * F + h] + cL[sl] * g0h, 0.f);
    S += w * h1;
    wns += w;
  }
  Sp[wv][h] = S;
  if (h == 0) { wnsL[wv] = wns; wselL[wv] = wsel; }
  __syncthreads();
  // ---- wave 0: combine partials, final two matvecs, store ----
  if (wv == 0) {
    float Sh = Sp[0][h] + Sp[1][h] + Sp[2][h] + Sp[3][h];
    float wnsT = wnsL[0] + wnsL[1] + wnsL[2] + wnsL[3];
    float wselT = wselL[0] + wselL[1] + wselL[2] + wselL[3];
    v0[0][h] = Sh;
    float a2h;
    MVB(a2h, wnsT * p.f0b[64 + h] + wselT * x11h, v0[0], (p.f0w + 4096));
    v1[0][h] = a2h;
    float o;
    MVB(o, p.cb[64 + h], v1[0], (p.cw + 4096));
    p.out[t * F + h] = o;
  }
}

extern "C" void kernel_launch(void* const* d_in, const int* in_sizes, int n_in,
                              void* d_out, int out_size, void* d_ws, size_t ws_size,
                              hipStream_t stream) {
  Params hp;
  hp.x = (const float*)d_in[0];
  hp.pos = (const int*)d_in[1];
  hp.esrc = (const int*)d_in[2];
  hp.edst = (const int*)d_in[3];
  hp.ew = (const float*)d_in[4];
  hp.f0w = (const float*)d_in[5];
  hp.f0b = (const float*)d_in[6];
  hp.f1w = (const float*)d_in[7];
  hp.f1b = (const float*)d_in[8];
  hp.cw = (const float*)d_in[9];
  hp.cb = (const float*)d_in[10];
  hp.out = (float*)d_out;
  const int N = in_sizes[0] / F;   // 10000
  hp.B = in_sizes[1];              // 16
  hp.E = in_sizes[2];              // 160000

  char* w = (char*)d_ws;
  size_t off = 0;
  auto take = [&](size_t nb) { size_t r = off; off += (nb + 255) & ~(size_t)255; return r; };
  // ---- zeroed by ONE small memset (contiguous from 0): cnt, TEn, bitmap ----
  size_t o_cnt = take(256);
  size_t o_ten = take(256);
  size_t o_bitmap = take(((size_t)N + 31) / 32 * 4);
  size_t zero_end = off;
  // ---- not zeroed (lazily initialized / fully overwritten before read) ----
  size_t o_sel = take(256);
  size_t o_slotb = take(256);
  size_t o_slotof = take((size_t)N * 4);
  size_t o_seb = take(SECAP * 4);
  size_t o_sed = take(SECAP * 4);
  size_t o_sew = take(SECAP * 4);
  size_t o_tesrc = take((size_t)hp.B * TCAP * 4);
  size_t o_tew = take((size_t)hp.B * TCAP * 4);
  size_t o_agg = take((size_t)FCAP * F * 4);
  size_t o_wsum = take((size_t)FCAP * 4);
  size_t o_zf = take((size_t)FCAP * F * 4);
  (void)ws_size;                   // ~5.7 MB total; ws is far larger

  hp.cnt = (int*)(w + o_cnt);
  hp.TEn = (int*)(w + o_ten);
  hp.bitmap = (unsigned*)(w + o_bitmap);
  hp.sel = (int*)(w + o_sel);
  hp.slotb = (int*)(w + o_slotb);
  hp.slot_of = (int*)(w + o_slotof);
  hp.SEb = (int*)(w + o_seb);
  hp.SEd = (int*)(w + o_sed);
  hp.SEw = (float*)(w + o_sew);
  hp.TEsrc2 = (int*)(w + o_tesrc);
  hp.TEw2 = (float*)(w + o_tew);
  hp.AGG = (float*)(w + o_agg);
  hp.wsum = (float*)(w + o_wsum);
  hp.zf = (float*)(w + o_zf);

  // node 1: tiny memset (~2 KB)
  hipMemsetAsync(d_ws, 0, zero_end, stream);
  // node 2: edge scan
  int nbE = (hp.E + BLK - 1) / BLK;
  if (nbE > 2048) nbE = 2048;
  kp_scan<<<nbE, BLK, 0, stream>>>(hp);
  // node 3: frontier aggregation
  kp_agg<<<nbE, BLK, 0, stream>>>(hp);
  // node 4: zf transform, parallel over frontier slots
  kp_zf<<<256, BLK, 0, stream>>>(hp);
  // node 5: epilogue (16 blocks x 4 waves)
  kp_epi<<<hp.B, BLK, 0, stream>>>(hp);
  (void)n_in; (void)out_size;
}